// Round 1
// 576.911 us; speedup vs baseline: 1.9781x; 1.9781x over previous
//
#include <hip/hip_runtime.h>
#include <stdint.h>

#define B_ROWS 32768
#define F_DIM  1024
#define H_DIM  512

typedef __attribute__((ext_vector_type(4))) float    floatx4;
typedef __attribute__((ext_vector_type(2))) __fp16   fp16x2;
typedef __attribute__((ext_vector_type(8))) _Float16 halfx8;

__device__ __forceinline__ void async_load16(const void* g, void* l) {
    __builtin_amdgcn_global_load_lds(
        (const __attribute__((address_space(1))) void*)g,
        (__attribute__((address_space(3))) void*)l, 16, 0, 0);
}

// --------------------------------------------------------------------------
// Wcomb[k,d,f] = sum_h Wqkv[k,d,h] * Wlin[k,h,f]   (d: 0-9 q, 10-19 k, 20-29 v)
// bcomb[k,d]   = b[k,d] + sum_h Wqkv[k,d,h] * blin[k,h]
// One block per (k,d) pair; rows 30,31 zero-padded for the N=32 MFMA tile.
// Weight row is wave-uniform (s_load); Wlin reads fully coalesced (4KB/row).
// --------------------------------------------------------------------------
__global__ __launch_bounds__(256) void k_prep(
    const float* __restrict__ Wlin, const float* __restrict__ blin,
    const float* __restrict__ Wq, const float* __restrict__ Wk,
    const float* __restrict__ Wv, const float* __restrict__ bq,
    const float* __restrict__ bk, const float* __restrict__ bv,
    ushort* __restrict__ Wcomb16, float* __restrict__ bcomb)
{
    const int k = blockIdx.x >> 5;
    const int d = blockIdx.x & 31;
    const int t = threadIdx.x;
    ushort4* outp = (ushort4*)(Wcomb16 + ((size_t)(k * 32 + d) << 10)) + t;

    if (d >= 30) {                       // pad rows: zero so MFMA cols 30/31 are benign
        ushort4 z; z.x = z.y = z.z = z.w = 0;
        *outp = z;
        if (t == 0) bcomb[k * 32 + d] = 0.f;
        return;
    }

    const float* wrow; float bias;
    if (d < 10)      { wrow = Wq + (size_t)(k * 10 + d) * H_DIM;      bias = bq[k * 10 + d]; }
    else if (d < 20) { wrow = Wk + (size_t)(k * 10 + d - 10) * H_DIM; bias = bk[k * 10 + d - 10]; }
    else             { wrow = Wv + (size_t)(k * 10 + d - 20) * H_DIM; bias = bv[k * 10 + d - 20]; }

    const float* wl = Wlin + ((size_t)k * H_DIM << 10) + t * 4;
    const float* bl = blin + (size_t)k * H_DIM;

    floatx4 acc = {0.f, 0.f, 0.f, 0.f};
    float bacc = 0.f;
    #pragma unroll 4
    for (int h = 0; h < H_DIM; ++h) {
        const float s = wrow[h];                         // wave-uniform
        const floatx4 x = *(const floatx4*)(wl + ((size_t)h << 10));
        acc.x += s * x.x; acc.y += s * x.y; acc.z += s * x.z; acc.w += s * x.w;
        bacc += s * bl[h];                               // uniform broadcast
    }
    union { _Float16 h[4]; ushort4 u; } o;
    o.h[0] = (_Float16)acc.x; o.h[1] = (_Float16)acc.y;
    o.h[2] = (_Float16)acc.z; o.h[3] = (_Float16)acc.w;
    *outp = o.u;
    if (t == 0) bcomb[k * 32 + d] = bias + bacc;
}

// --------------------------------------------------------------------------
// qkv_t[(k*30+d)*B + b] = sum_f w_k[b,f] * Wcomb[k,d,f] + bcomb[k,d]
// Skinny GEMM M=128/block, N=32, K=1024, Kc=64. A (w_k, f32) staged via
// global_load_lds with SOURCE-side 16B-slot XOR swizzle (^ row&7) so the
// stride-256B/128B fragment reads distribute uniformly over the 32 banks.
// Each w element is fetched from HBM exactly once across the whole grid.
// --------------------------------------------------------------------------
__global__ __launch_bounds__(256) void k_main(
    const float* __restrict__ w0, const float* __restrict__ w1,
    const float* __restrict__ w2, const float* __restrict__ w3,
    const ushort* __restrict__ Wcomb16, const float* __restrict__ bcomb,
    float* __restrict__ qkv_t)
{
    __shared__ float  As[128 * 64];   // 32 KiB, [row][64] f32, slot-swizzled content
    __shared__ ushort Bs[32 * 64];    // 4 KiB,  [n][64] f16,  slot-swizzled content

    const int tid     = threadIdx.x;
    const int bx      = blockIdx.x;
    const int k       = bx & 3;
    const int rowBase = (bx >> 2) * 128;

    const float* A = (k == 0) ? w0 : (k == 1) ? w1 : (k == 2) ? w2 : w3;

    // A staging: 16 rows/issue, 8 issues. LDS dest linear (tid*16B); global
    // source column pre-swizzled so LDS[row][slot] = global[row][slot ^ (row&7)].
    const int arow  = tid >> 4;                       // 0..15
    const int ascol = ((tid & 15) ^ (arow & 7)) * 4;  // floats
    // B staging: 32 rows, 1 issue (4 KiB).
    const int brow  = tid >> 3;                       // 0..31
    const int bscol = ((tid & 7) ^ (brow & 7)) * 8;   // f16 elems

    const float*  gA0 = A + (size_t)(rowBase + arow) * F_DIM + ascol;
    const ushort* gB0 = Wcomb16 + (size_t)(k * 32 + brow) * 1024 + bscol;
    float*  lA = &As[tid * 4];
    ushort* lB = &Bs[tid * 8];

    const int wv = tid >> 6;
    const int ln = tid & 63;
    const int lr = ln & 15;
    const int lq = ln >> 4;
    const int sw = lr & 7;            // read-side swizzle key (row&7 == lr&7)

    floatx4 acc[2][2] = {};

    for (int kc = 0; kc < F_DIM; kc += 64) {
        __syncthreads();              // prior compute done before overwriting LDS
        #pragma unroll
        for (int it = 0; it < 8; ++it)
            async_load16(gA0 + kc + it * 16 * F_DIM, lA + it * 16 * 64);
        async_load16(gB0 + kc, lB);
        __syncthreads();              // drains vmcnt(0)

        #pragma unroll
        for (int ks = 0; ks < 2; ++ks) {
            halfx8 af[2];
            #pragma unroll
            for (int i = 0; i < 2; ++i) {
                const int rbase = (wv * 32 + i * 16 + lr) * 64;
                const int s0 = (ks * 8 + lq * 2) ^ sw;      // 16B slot of k-elems 0..3
                const floatx4 f0 = *(const floatx4*)&As[rbase + s0 * 4];
                const floatx4 f1 = *(const floatx4*)&As[rbase + (s0 ^ 1) * 4];
                union { fp16x2 h2[4]; halfx8 h8; } u;
                u.h2[0] = __builtin_amdgcn_cvt_pkrtz(f0.x, f0.y);
                u.h2[1] = __builtin_amdgcn_cvt_pkrtz(f0.z, f0.w);
                u.h2[2] = __builtin_amdgcn_cvt_pkrtz(f1.x, f1.y);
                u.h2[3] = __builtin_amdgcn_cvt_pkrtz(f1.z, f1.w);
                af[i] = u.h8;
            }
            #pragma unroll
            for (int j = 0; j < 2; ++j) {
                const int bs = (ks * 4 + lq) ^ sw;          // 16B slot (8 f16)
                const halfx8 bf = *(const halfx8*)&Bs[(j * 16 + lr) * 64 + bs * 8];
                acc[0][j] = __builtin_amdgcn_mfma_f32_16x16x32_f16(af[0], bf, acc[0][j], 0, 0, 0);
                acc[1][j] = __builtin_amdgcn_mfma_f32_16x16x32_f16(af[1], bf, acc[1][j], 0, 0, 0);
            }
        }
    }

    // epilogue: +bcomb, store transposed. C/D: col=lane&15, row=(lane>>4)*4+reg.
    // Transposed layout makes reg-index r = consecutive b -> float4 stores.
    const float* bc = bcomb + k * 32;
    #pragma unroll
    for (int j = 0; j < 2; ++j) {
        const int d = j * 16 + lr;
        if (d < 30) {
            const float bias = bc[d];
            float* outd = qkv_t + (size_t)(k * 30 + d) * B_ROWS;
            #pragma unroll
            for (int i = 0; i < 2; ++i) {
                const int r0 = rowBase + wv * 32 + i * 16 + lq * 4;
                floatx4 o = acc[i][j];
                o.x += bias; o.y += bias; o.z += bias; o.w += bias;
                *(floatx4*)(outd + r0) = o;
            }
        }
    }
}

// -------------------------------------------- per-b attention + heads epilogue
__global__ __launch_bounds__(128) void k_final(
    const float* __restrict__ qkv_t, const float* __restrict__ Wfin,
    const float* __restrict__ bfin,
    float* __restrict__ outputs, float* __restrict__ attn)
{
    __shared__ float sW[400];
    __shared__ float sb[40];
    const int t = threadIdx.x;
    for (int i = t; i < 400; i += 128) sW[i] = Wfin[i];
    if (t < 40) sb[t] = bfin[t];
    __syncthreads();

    const int b = blockIdx.x * 128 + t;
    const float* pt = qkv_t + b;                     // column reads: fully coalesced
    float q[4][10], kk[4][10], v0[10];
    #pragma unroll
    for (int k = 0; k < 4; ++k)
        #pragma unroll
        for (int e = 0; e < 10; ++e) {
            q[k][e]  = pt[(size_t)(k * 30 + e) * B_ROWS];
            kk[k][e] = pt[(size_t)(k * 30 + 10 + e) * B_ROWS];
        }
    #pragma unroll
    for (int m = 0; m < 10; ++m) v0[m] = pt[(size_t)(20 + m) * B_ROWS];  // v, head 0

    float out0[10];
    #pragma unroll
    for (int e = 0; e < 10; ++e) out0[e] = 0.f;
    float* ab = attn + (size_t)b * 100;
    const float inv = 0.31622776601683794f;  // 1/sqrt(10)

    // attn[b,e,m] = softmax over e (axis=1) of (sum_k q[k][e]*kk[k][m])/sqrt(E)
    #pragma unroll
    for (int m = 0; m < 10; ++m) {
        float col[10]; float mx = -1e30f;
        #pragma unroll
        for (int e = 0; e < 10; ++e) {
            col[e] = (q[0][e]*kk[0][m] + q[1][e]*kk[1][m]
                    + q[2][e]*kk[2][m] + q[3][e]*kk[3][m]) * inv;
            mx = fmaxf(mx, col[e]);
        }
        float s = 0.f;
        #pragma unroll
        for (int e = 0; e < 10; ++e) { col[e] = __expf(col[e] - mx); s += col[e]; }
        const float r = 1.f / s;
        #pragma unroll
        for (int e = 0; e < 10; ++e) {
            const float a = col[e] * r;
            ab[e * 10 + m] = a;
            out0[e] += a * v0[m];     // att_out[b,0,e] accumulation
        }
    }

    float oc[10];
    #pragma unroll
    for (int c = 0; c < 10; ++c) oc[c] = 0.f;
    #pragma unroll
    for (int k = 0; k < 4; ++k) {
        float lg[10]; float mx = -1e30f;
        #pragma unroll
        for (int c = 0; c < 10; ++c) {
            float s = sb[k * 10 + c];
            #pragma unroll
            for (int e = 0; e < 10; ++e) s += out0[e] * sW[(k * 10 + c) * 10 + e];
            lg[c] = s; mx = fmaxf(mx, s);
        }
        float s = 0.f;
        #pragma unroll
        for (int c = 0; c < 10; ++c) { lg[c] = __expf(lg[c] - mx); s += lg[c]; }
        const float r = 0.25f / s;
        #pragma unroll
        for (int c = 0; c < 10; ++c) oc[c] += lg[c] * r;
    }
    #pragma unroll
    for (int c = 0; c < 10; ++c) outputs[(size_t)b * 10 + c] = oc[c];
}

extern "C" void kernel_launch(void* const* d_in, const int* in_sizes, int n_in,
                              void* d_out, int out_size, void* d_ws, size_t ws_size,
                              hipStream_t stream) {
    const float* w0   = (const float*)d_in[0];
    const float* w1   = (const float*)d_in[1];
    const float* w2   = (const float*)d_in[2];
    const float* w3   = (const float*)d_in[3];
    const float* Wlin = (const float*)d_in[4];
    const float* blin = (const float*)d_in[5];
    const float* Wq   = (const float*)d_in[6];
    const float* bq   = (const float*)d_in[7];
    const float* Wk   = (const float*)d_in[8];
    const float* bk   = (const float*)d_in[9];
    const float* Wv   = (const float*)d_in[10];
    const float* bv   = (const float*)d_in[11];
    const float* Wfin = (const float*)d_in[12];
    const float* bfin = (const float*)d_in[13];

    char* ws = (char*)d_ws;
    ushort* Wcomb16 = (ushort*)ws;                          // 256 KiB  [4][32][1024] f16
    float*  bcomb   = (float*)(ws + ((size_t)256 << 10));   // 512 B    [4][32]
    float*  qkv_t   = (float*)(ws + ((size_t)1 << 20));     // 15 MiB   [120][B] transposed

    float* outputs = (float*)d_out;
    float* attn    = outputs + (size_t)B_ROWS * 10;

    k_prep <<<128,  256, 0, stream>>>(Wlin, blin, Wq, Wk, Wv, bq, bk, bv, Wcomb16, bcomb);
    k_main <<<1024, 256, 0, stream>>>(w0, w1, w2, w3, Wcomb16, bcomb, qkv_t);
    k_final<<<256,  128, 0, stream>>>(qkv_t, Wfin, bfin, outputs, attn);
}

// Round 2
// 518.377 us; speedup vs baseline: 2.2015x; 1.1129x over previous
//
#include <hip/hip_runtime.h>
#include <stdint.h>

#define B_ROWS 32768
#define F_DIM  1024
#define H_DIM  512
#define RS     32832   // qkv_t row stride: B_ROWS + 64 floats, breaks 2^17 aliasing

typedef __attribute__((ext_vector_type(4))) float    floatx4;
typedef __attribute__((ext_vector_type(2))) __fp16   fp16x2;
typedef __attribute__((ext_vector_type(8))) _Float16 halfx8;

__device__ __forceinline__ void async_load16(const void* g, void* l) {
    __builtin_amdgcn_global_load_lds(
        (const __attribute__((address_space(1))) void*)g,
        (__attribute__((address_space(3))) void*)l, 16, 0, 0);
}

// --------------------------------------------------------------------------
// Wcomb[k,d,f] = sum_h Wqkv[k,d,h] * Wlin[k,h,f]   (d: 0-9 q, 10-19 k, 20-29 v)
// bcomb[k,d]   = b[k,d] + sum_h Wqkv[k,d,h] * blin[k,h]
// 2 blocks per (k,d): each handles half the f-columns. 256 blocks -> all CUs.
// --------------------------------------------------------------------------
__global__ __launch_bounds__(128) void k_prep(
    const float* __restrict__ Wlin, const float* __restrict__ blin,
    const float* __restrict__ Wq, const float* __restrict__ Wk,
    const float* __restrict__ Wv, const float* __restrict__ bq,
    const float* __restrict__ bk, const float* __restrict__ bv,
    ushort* __restrict__ Wcomb16, float* __restrict__ bcomb)
{
    const int bx   = blockIdx.x;
    const int k    = bx >> 6;
    const int d    = (bx >> 1) & 31;
    const int half = bx & 1;
    const int t    = threadIdx.x;
    const int col  = half * 512 + t * 4;      // f-column (floats)
    ushort4* outp = (ushort4*)(Wcomb16 + ((size_t)(k * 32 + d) << 10) + col);

    if (d >= 30) {                  // pad rows: zero so MFMA cols 30/31 are benign
        ushort4 z; z.x = z.y = z.z = z.w = 0;
        *outp = z;
        if (half == 0 && t == 0) bcomb[k * 32 + d] = 0.f;
        return;
    }

    const float* wrow; float bias;
    if (d < 10)      { wrow = Wq + (size_t)(k * 10 + d) * H_DIM;      bias = bq[k * 10 + d]; }
    else if (d < 20) { wrow = Wk + (size_t)(k * 10 + d - 10) * H_DIM; bias = bk[k * 10 + d - 10]; }
    else             { wrow = Wv + (size_t)(k * 10 + d - 20) * H_DIM; bias = bv[k * 10 + d - 20]; }

    const float* wl = Wlin + ((size_t)k * H_DIM << 10) + col;
    const float* bl = blin + (size_t)k * H_DIM;

    floatx4 acc = {0.f, 0.f, 0.f, 0.f};
    float bacc = 0.f;
    #pragma unroll 8
    for (int h = 0; h < H_DIM; ++h) {
        const float s = wrow[h];                         // wave-uniform
        const floatx4 x = *(const floatx4*)(wl + ((size_t)h << 10));
        acc.x += s * x.x; acc.y += s * x.y; acc.z += s * x.z; acc.w += s * x.w;
        bacc += s * bl[h];
    }
    union { _Float16 h[4]; ushort4 u; } o;
    o.h[0] = (_Float16)acc.x; o.h[1] = (_Float16)acc.y;
    o.h[2] = (_Float16)acc.z; o.h[3] = (_Float16)acc.w;
    *outp = o.u;
    if (half == 0 && t == 0) bcomb[k * 32 + d] = bias + bacc;
}

// --------------------------------------------------------------------------
// qkv_t[(k*30+d)*RS + b] = sum_f w_k[b,f] * Wcomb[k,d,f] + bcomb[k,d]
// Skinny GEMM M=128/block, N=32, K=1024, Kc=64, DOUBLE-BUFFERED 2-phase:
// stage chunk t+1 -> counted s_waitcnt vmcnt(9) (chunk t done, 9 in flight)
// -> raw s_barrier -> compute chunk t -> raw s_barrier. HBM loads stay in
// flight across the barriers; no vmcnt(0) drain in the main loop.
// --------------------------------------------------------------------------
__global__ __launch_bounds__(256) void k_main(
    const float* __restrict__ w0, const float* __restrict__ w1,
    const float* __restrict__ w2, const float* __restrict__ w3,
    const ushort* __restrict__ Wcomb16, const float* __restrict__ bcomb,
    float* __restrict__ qkv_t)
{
    __shared__ float  As[2][128 * 64];   // 2 x 32 KiB, slot-swizzled content
    __shared__ ushort Bs[2][32 * 64];    // 2 x 4  KiB, slot-swizzled content

    const int tid     = threadIdx.x;
    const int bx      = blockIdx.x;
    const int k       = bx & 3;
    const int rowBase = (bx >> 2) * 128;

    const float* A = (k == 0) ? w0 : (k == 1) ? w1 : (k == 2) ? w2 : w3;

    // A staging: 16 rows/issue, 8 issues. LDS dest linear (tid*16B); global
    // source column pre-swizzled: LDS[row][slot] = global[row][slot ^ (row&7)].
    const int arow  = tid >> 4;                       // 0..15
    const int ascol = ((tid & 15) ^ (arow & 7)) * 4;  // floats
    const int brow  = tid >> 3;                       // 0..31
    const int bscol = ((tid & 7) ^ (brow & 7)) * 8;   // f16 elems

    const float*  gA0 = A + (size_t)(rowBase + arow) * F_DIM + ascol;
    const ushort* gB0 = Wcomb16 + (size_t)(k * 32 + brow) * 1024 + bscol;

    const int wv = tid >> 6;
    const int ln = tid & 63;
    const int lr = ln & 15;
    const int lq = ln >> 4;
    const int sw = lr & 7;            // read-side swizzle key (row&7 == lr&7)

    floatx4 acc[2][2] = {};

    #define STAGE(buf, kc) do {                                            \
        float*  lAb = &As[buf][tid * 4];                                   \
        ushort* lBb = &Bs[buf][tid * 8];                                   \
        _Pragma("unroll")                                                  \
        for (int it = 0; it < 8; ++it)                                     \
            async_load16(gA0 + (kc) + it * 16 * F_DIM, lAb + it * 16 * 64);\
        async_load16(gB0 + (kc), lBb);                                     \
    } while (0)

    STAGE(0, 0);                       // prologue: chunk 0 -> buf 0

    #pragma unroll 2
    for (int t = 0; t < 16; ++t) {
        const int cur = t & 1;
        if (t < 15) {
            STAGE(cur ^ 1, (t + 1) * 64);                 // 9 loads in flight
            asm volatile("s_waitcnt vmcnt(9)" ::: "memory");  // chunk t done
        } else {
            asm volatile("s_waitcnt vmcnt(0)" ::: "memory");
        }
        __builtin_amdgcn_sched_barrier(0);
        __builtin_amdgcn_s_barrier();
        __builtin_amdgcn_sched_barrier(0);

        #pragma unroll
        for (int ks = 0; ks < 2; ++ks) {
            halfx8 af[2];
            #pragma unroll
            for (int i = 0; i < 2; ++i) {
                const int rbase = (wv * 32 + i * 16 + lr) * 64;
                const int s0 = (ks * 8 + lq * 2) ^ sw;      // 16B slot of k-elems
                const floatx4 f0 = *(const floatx4*)&As[cur][rbase + s0 * 4];
                const floatx4 f1 = *(const floatx4*)&As[cur][rbase + (s0 ^ 1) * 4];
                union { fp16x2 h2[4]; halfx8 h8; } u;
                u.h2[0] = __builtin_amdgcn_cvt_pkrtz(f0.x, f0.y);
                u.h2[1] = __builtin_amdgcn_cvt_pkrtz(f0.z, f0.w);
                u.h2[2] = __builtin_amdgcn_cvt_pkrtz(f1.x, f1.y);
                u.h2[3] = __builtin_amdgcn_cvt_pkrtz(f1.z, f1.w);
                af[i] = u.h8;
            }
            #pragma unroll
            for (int j = 0; j < 2; ++j) {
                const int bs = (ks * 4 + lq) ^ sw;          // 16B slot (8 f16)
                const halfx8 bf = *(const halfx8*)&Bs[cur][(j * 16 + lr) * 64 + bs * 8];
                acc[0][j] = __builtin_amdgcn_mfma_f32_16x16x32_f16(af[0], bf, acc[0][j], 0, 0, 0);
                acc[1][j] = __builtin_amdgcn_mfma_f32_16x16x32_f16(af[1], bf, acc[1][j], 0, 0, 0);
            }
        }
        __builtin_amdgcn_sched_barrier(0);
        __builtin_amdgcn_s_barrier();   // all waves done reading buf cur
    }
    #undef STAGE

    // epilogue: +bcomb, store transposed (padded stride RS).
    // C/D: col=lane&15, row=(lane>>4)*4+reg -> reg index = consecutive b.
    const float* bc = bcomb + k * 32;
    #pragma unroll
    for (int j = 0; j < 2; ++j) {
        const int d = j * 16 + lr;
        if (d < 30) {
            const float bias = bc[d];
            float* outd = qkv_t + (size_t)(k * 30 + d) * RS;
            #pragma unroll
            for (int i = 0; i < 2; ++i) {
                const int r0 = rowBase + wv * 32 + i * 16 + lq * 4;
                floatx4 o = acc[i][j];
                o.x += bias; o.y += bias; o.z += bias; o.w += bias;
                *(floatx4*)(outd + r0) = o;
            }
        }
    }
}

// -------------------------------------------- per-b attention + heads epilogue
// attn staged in LDS (padded x101: conflict-free), written back fully
// coalesced (512B per wave-instruction). Same for outputs.
__global__ __launch_bounds__(128) void k_final(
    const float* __restrict__ qkv_t, const float* __restrict__ Wfin,
    const float* __restrict__ bfin,
    float* __restrict__ outputs, float* __restrict__ attn)
{
    __shared__ float sW[400];
    __shared__ float sb[40];
    __shared__ float sA[128 * 101];   // 50.5 KiB attn staging, +1 pad
    const int t = threadIdx.x;
    for (int i = t; i < 400; i += 128) sW[i] = Wfin[i];
    if (t < 40) sb[t] = bfin[t];
    __syncthreads();

    const int b = blockIdx.x * 128 + t;
    const float* pt = qkv_t + b;                     // coalesced column reads
    float q[4][10], kk[4][10], v0[10];
    #pragma unroll
    for (int k = 0; k < 4; ++k)
        #pragma unroll
        for (int e = 0; e < 10; ++e) {
            q[k][e]  = pt[(size_t)(k * 30 + e) * RS];
            kk[k][e] = pt[(size_t)(k * 30 + 10 + e) * RS];
        }
    #pragma unroll
    for (int m = 0; m < 10; ++m) v0[m] = pt[(size_t)(20 + m) * RS];  // v, head 0

    float out0[10];
    #pragma unroll
    for (int e = 0; e < 10; ++e) out0[e] = 0.f;
    float* sAr = &sA[t * 101];
    const float inv = 0.31622776601683794f;  // 1/sqrt(10)

    // attn[b,e,m] = softmax over e (axis=1) of (sum_k q[k][e]*kk[k][m])/sqrt(E)
    #pragma unroll
    for (int m = 0; m < 10; ++m) {
        float col[10]; float mx = -1e30f;
        #pragma unroll
        for (int e = 0; e < 10; ++e) {
            col[e] = (q[0][e]*kk[0][m] + q[1][e]*kk[1][m]
                    + q[2][e]*kk[2][m] + q[3][e]*kk[3][m]) * inv;
            mx = fmaxf(mx, col[e]);
        }
        float s = 0.f;
        #pragma unroll
        for (int e = 0; e < 10; ++e) { col[e] = __expf(col[e] - mx); s += col[e]; }
        const float r = 1.f / s;
        #pragma unroll
        for (int e = 0; e < 10; ++e) {
            const float a = col[e] * r;
            sAr[e * 10 + m] = a;
            out0[e] += a * v0[m];     // att_out[b,0,e] accumulation
        }
    }

    float oc[10];
    #pragma unroll
    for (int c = 0; c < 10; ++c) oc[c] = 0.f;
    #pragma unroll
    for (int k = 0; k < 4; ++k) {
        float lg[10]; float mx = -1e30f;
        #pragma unroll
        for (int c = 0; c < 10; ++c) {
            float s = sb[k * 10 + c];
            #pragma unroll
            for (int e = 0; e < 10; ++e) s += out0[e] * sW[(k * 10 + c) * 10 + e];
            lg[c] = s; mx = fmaxf(mx, s);
        }
        float s = 0.f;
        #pragma unroll
        for (int c = 0; c < 10; ++c) { lg[c] = __expf(lg[c] - mx); s += lg[c]; }
        const float r = 0.25f / s;
        #pragma unroll
        for (int c = 0; c < 10; ++c) oc[c] += lg[c] * r;
    }

    // ---- coalesced attn writeback: block tile = 128 b x 100 = 12800 floats
    __syncthreads();
    const size_t abase = (size_t)blockIdx.x * 12800;
    for (int i = t; i < 12800; i += 128) {
        const int bl = i / 100;                  // const-div -> magic mul
        attn[abase + i] = sA[bl * 101 + (i - bl * 100)];
    }

    // ---- coalesced outputs writeback: 128 b x 10 = 1280 floats
    __syncthreads();
    #pragma unroll
    for (int c = 0; c < 10; ++c) sA[t * 11 + c] = oc[c];
    __syncthreads();
    const size_t obase = (size_t)blockIdx.x * 1280;
    for (int i = t; i < 1280; i += 128) {
        const int bl = i / 10;
        outputs[obase + i] = sA[bl * 11 + (i - bl * 10)];
    }
}

extern "C" void kernel_launch(void* const* d_in, const int* in_sizes, int n_in,
                              void* d_out, int out_size, void* d_ws, size_t ws_size,
                              hipStream_t stream) {
    const float* w0   = (const float*)d_in[0];
    const float* w1   = (const float*)d_in[1];
    const float* w2   = (const float*)d_in[2];
    const float* w3   = (const float*)d_in[3];
    const float* Wlin = (const float*)d_in[4];
    const float* blin = (const float*)d_in[5];
    const float* Wq   = (const float*)d_in[6];
    const float* bq   = (const float*)d_in[7];
    const float* Wk   = (const float*)d_in[8];
    const float* bk   = (const float*)d_in[9];
    const float* Wv   = (const float*)d_in[10];
    const float* bv   = (const float*)d_in[11];
    const float* Wfin = (const float*)d_in[12];
    const float* bfin = (const float*)d_in[13];

    char* ws = (char*)d_ws;
    ushort* Wcomb16 = (ushort*)ws;                          // 256 KiB  [4][32][1024] f16
    float*  bcomb   = (float*)(ws + ((size_t)256 << 10));   // 512 B    [4][32]
    float*  qkv_t   = (float*)(ws + ((size_t)1 << 20));     // ~15.8 MiB [120][RS]

    float* outputs = (float*)d_out;
    float* attn    = outputs + (size_t)B_ROWS * 10;

    k_prep <<<256,  128, 0, stream>>>(Wlin, blin, Wq, Wk, Wv, bq, bk, bv, Wcomb16, bcomb);
    k_main <<<1024, 256, 0, stream>>>(w0, w1, w2, w3, Wcomb16, bcomb, qkv_t);
    k_final<<<256,  128, 0, stream>>>(qkv_t, Wfin, bfin, outputs, attn);
}